// Round 9
// baseline (86.872 us; speedup 1.0000x reference)
//
#include <hip/hip_runtime.h>
#include <math.h>

#define QMAX 128   // wavelet support: gauss fp32-underflows to exact 0 beyond t~82
#define ZCUT 1920  // outputs p < ZCUT are exactly zero (x index p-1920 < 0)
#define HALF 1088  // nonzero outputs per half-row (2176 = 2*HALF)
#define XWIN 1216  // x window floats needed per half
#define XS_SZ 1280

typedef float vfloat4 __attribute__((ext_vector_type(4)));

// ---------------- Kernel 1: fused W[k] build + FIR conv of half-rows -> ws ---------
// (byte-identical to R6's conv_half; launched 3x this round purely to measure its
// duration via dur_us = base + 2*C. Idempotent: same inputs -> same ws values.)
__global__ __launch_bounds__(256) void conv_half(const float* __restrict__ x,
                                                 const float* __restrict__ scales,
                                                 const float* __restrict__ f_mod,
                                                 const float* __restrict__ poly_mod,
                                                 const float* __restrict__ exp_mod,
                                                 const float* __restrict__ frac_order,
                                                 const float* __restrict__ phase_mod,
                                                 const int* __restrict__ istep,
                                                 float* __restrict__ ws) {
    __shared__ __attribute__((aligned(16))) float xs[XS_SZ];
    __shared__ __attribute__((aligned(16))) float Wl[QMAX];
    __shared__ float wsum[2];

    const int blk = blockIdx.x;
    const int bk = blk >> 1;         // 0..255
    const int h = blk & 1;
    const int k = bk & 15;
    const int tid = threadIdx.x;
    const int Ph = ZCUT + h * HALF;  // first output index of this half

    // ---- stage xs[i] = x[Ph-2047+i], i in [0,XWIN); zeros outside ----
    const float* xrow = x + (size_t)bk * 4096;
    const int x0 = Ph - 2047;        // h=0: -127, h=1: 961
    for (int li = tid; li < XS_SZ; li += 256) {
        int g = x0 + li;
        xs[li] = (g >= 0 && li < XWIN) ? xrow[g] : 0.0f;  // max g = 2176 < 4096
    }

    // ---- threads 0..127 compute wavelet taps ----
    float amp = 0.0f, rw = 0.0f, iw = 0.0f;
    if (tid < QMAX) {
        const int i = istep[0];
        const float PI2 = 6.28318530717958647692f;
        const float f = 1.0f / scales[k];
        const float fm = f_mod[i];
        const float* pm = poly_mod + i * 14;
        const float em0 = exp_mod[i];
        const float* fo = frac_order + i * 12;

        const float sigma = fmaxf(fm / (PI2 * f), 1e-6f);
        const float tf = (float)tid;
        const float arg = PI2 * f * tf;
        const float br = cosf(arg);
        const float bi = sinf(arg);

        float rp = pm[0];
        float sign = -1.0f;
        for (int j = 0; j < 6; ++j) {
            float c = (float)(j + 2);
            float sp = (tf > 0.0f) ? powf(tf, fo[j]) : 0.0f;
            rp += sign * (sp * c / powf(sigma, fo[j]) * c * pm[j + 1]);
            sign = -sign;
        }
        float ipoly = pm[7];
        sign = -1.0f;
        for (int j = 6; j < 12; ++j) {
            float sp = (tf > 0.0f) ? powf(tf, fo[j]) : 0.0f;
            float term;
            if (j == 9) {
                term = sp * 5.0f / (powf(sigma, fo[j]) * 5.0f) * pm[j + 2];
            } else {
                float c = (float)(j - 4);
                term = sp * c / powf(sigma, fo[j]) * c * pm[j + 2];
            }
            ipoly += sign * term;
            sign = -sign;
        }

        const float gauss = em0 * expf(-tf * tf / (2.0f * sigma * sigma));
        rw = br * rp * gauss;
        iw = bi * ipoly * gauss;
        amp = rw + iw;

        float sq = amp * amp;
        #pragma unroll
        for (int off = 32; off > 0; off >>= 1) sq += __shfl_xor(sq, off, 64);
        if ((tid & 63) == 0) wsum[tid >> 6] = sq;
    }
    __syncthreads();

    if (tid < QMAX) {
        const int i = istep[0];
        const float* ph = phase_mod + i * 3;
        const float norm = sqrtf(wsum[0] + wsum[1]);
        const float samp = amp / norm;
        const float phase = atan2f(iw, rw);
        const float sphi = sinf(phase);
        const float cphi = cosf(phase);
        const float snc = (phase != 0.0f) ? (sphi / phase) : 1.0f;  // sinc(phase/pi)
        Wl[tid] = (samp * sphi * ph[0]) * (samp * cphi * ph[1]) * (samp * snc * ph[2]);
    }
    __syncthreads();

    // ---- conv: 272 float4s per half (threads 0..255 one each; 0..15 a second) ----
    float* wrow = ws + (size_t)bk * 4096;
    #pragma unroll
    for (int e = 0; e < 2; ++e) {
        const int fi = tid + e * 256;
        if (e == 1 && fi >= HALF / 4) break;
        const int p = Ph + 4 * fi;
        const int base = 4 * fi;     // xs[base+q] = x[p+q-2047]
        float acc[4] = {0.0f, 0.0f, 0.0f, 0.0f};
        float4 xcur = *(const float4*)&xs[base];
        for (int q = 0; q < QMAX; q += 4) {
            float4 w4 = *(const float4*)&Wl[q];
            float4 xnxt = *(const float4*)&xs[base + q + 4];
            float win[8] = {xcur.x, xcur.y, xcur.z, xcur.w,
                            xnxt.x, xnxt.y, xnxt.z, xnxt.w};
            float wv[4] = {w4.x, w4.y, w4.z, w4.w};
            #pragma unroll
            for (int j = 0; j < 4; ++j) {
                #pragma unroll
                for (int r = 0; r < 4; ++r) {
                    acc[r] = fmaf(win[r + j], wv[j], acc[r]);
                }
            }
            xcur = xnxt;
        }
        *(float4*)&wrow[p] = make_float4(acc[0], acc[1], acc[2], acc[3]);
    }
}

// ---------------- Kernel 2: fill-shaped replicate ws -> out (R6's, unchanged) ------
__global__ __launch_bounds__(256) void replicate_rows(const float* __restrict__ ws,
                                                      float* __restrict__ out) {
    const int g = blockIdx.x;        // 0..511
    const int m0 = g * 8;
    const int b = m0 >> 8;           // all 8 rows share b (8 | 256)
    const int tid = threadIdx.x;
    const vfloat4 zero = {0.0f, 0.0f, 0.0f, 0.0f};

    #pragma unroll
    for (int r = 0; r < 8; ++r) {
        const int m = m0 + r;
        const int k = m & 15;
        const float* __restrict__ src = ws + ((size_t)b * 16 + k) * 4096;
        float* __restrict__ dst = out + (size_t)m * 4096;
        #pragma unroll
        for (int v = 0; v < 4; ++v) {
            const int e = 4 * (tid + 256 * v);
            vfloat4 val = (e >= ZCUT) ? *(const vfloat4*)&src[e] : zero;
            __builtin_nontemporal_store(val, (vfloat4*)&dst[e]);
        }
    }
}

extern "C" void kernel_launch(void* const* d_in, const int* in_sizes, int n_in,
                              void* d_out, int out_size, void* d_ws, size_t ws_size,
                              hipStream_t stream) {
    const float* x          = (const float*)d_in[0];
    const float* scales     = (const float*)d_in[1];
    const float* f_mod      = (const float*)d_in[2];
    const float* poly_mod   = (const float*)d_in[3];
    const float* exp_mod    = (const float*)d_in[4];
    const float* frac_order = (const float*)d_in[5];
    const float* phase_mod  = (const float*)d_in[6];
    const int*   istep      = (const int*)d_in[7];
    float* out = (float*)d_out;
    float* rows = (float*)d_ws;  // 256 rows x 4096 floats = 4 MB

    // MEASUREMENT ROUND: conv_half launched 3x (idempotent; sequential in graph).
    // dur_us = (C + R) + 2C = 35.5 + 2*C_conv  ->  solves the component split.
    conv_half<<<dim3(512), dim3(256), 0, stream>>>(
        x, scales, f_mod, poly_mod, exp_mod, frac_order, phase_mod, istep, rows);
    conv_half<<<dim3(512), dim3(256), 0, stream>>>(
        x, scales, f_mod, poly_mod, exp_mod, frac_order, phase_mod, istep, rows);
    conv_half<<<dim3(512), dim3(256), 0, stream>>>(
        x, scales, f_mod, poly_mod, exp_mod, frac_order, phase_mod, istep, rows);

    replicate_rows<<<dim3(512), dim3(256), 0, stream>>>(rows, out);
}

// Round 10
// 40.964 us; speedup vs baseline: 2.1207x; 2.1207x over previous
//
#include <hip/hip_runtime.h>
#include <math.h>

#define QMAX 128   // wavelet support: gauss fp32-underflows to exact 0 beyond t~82
#define ZCUT 1920  // outputs p < ZCUT are exactly zero (x index p-1920 < 0)
#define ESPAN 272  // outputs per block: (4096-1920)/8
#define EF4 68     // float4s per block = ESPAN/4
#define XS_SZ 400  // window floats: ESPAN + 127, padded to 400

typedef float vfloat4 __attribute__((ext_vector_type(4)));

// ---------------- Kernel 1: build W[16][QMAX] -> ws[0..2048) ----------------
__global__ void wavelet_build(const float* __restrict__ scales,
                              const float* __restrict__ f_mod,
                              const float* __restrict__ poly_mod,
                              const float* __restrict__ exp_mod,
                              const float* __restrict__ frac_order,
                              const float* __restrict__ phase_mod,
                              const int* __restrict__ istep,
                              float* __restrict__ Wout) {
    const int k = blockIdx.x;   // scale 0..15
    const int t = threadIdx.x;  // 0..127
    const int i = istep[0];
    const float PI2 = 6.28318530717958647692f;

    const float f = 1.0f / scales[k];
    const float fm = f_mod[i];
    const float* pm = poly_mod + i * 14;
    const float em0 = exp_mod[i];
    const float* fo = frac_order + i * 12;
    const float* ph = phase_mod + i * 3;

    const float sigma = fmaxf(fm / (PI2 * f), 1e-6f);
    const float tf = (float)t;
    const float arg = PI2 * f * tf;
    const float br = cosf(arg);
    const float bi = sinf(arg);

    float rp = pm[0];
    float sign = -1.0f;
    for (int j = 0; j < 6; ++j) {
        float c = (float)(j + 2);
        float sp = (tf > 0.0f) ? powf(tf, fo[j]) : 0.0f;
        rp += sign * (sp * c / powf(sigma, fo[j]) * c * pm[j + 1]);
        sign = -sign;
    }
    float ipoly = pm[7];
    sign = -1.0f;
    for (int j = 6; j < 12; ++j) {
        float sp = (tf > 0.0f) ? powf(tf, fo[j]) : 0.0f;
        float term;
        if (j == 9) {
            term = sp * 5.0f / (powf(sigma, fo[j]) * 5.0f) * pm[j + 2];
        } else {
            float c = (float)(j - 4);
            term = sp * c / powf(sigma, fo[j]) * c * pm[j + 2];
        }
        ipoly += sign * term;
        sign = -sign;
    }

    const float gauss = em0 * expf(-tf * tf / (2.0f * sigma * sigma));
    const float rw = br * rp * gauss;
    const float iw = bi * ipoly * gauss;
    const float amp = rw + iw;

    float sq = amp * amp;
    #pragma unroll
    for (int off = 32; off > 0; off >>= 1) sq += __shfl_xor(sq, off, 64);
    __shared__ float wsum[2];
    if ((t & 63) == 0) wsum[t >> 6] = sq;
    __syncthreads();
    const float norm = sqrtf(wsum[0] + wsum[1]);

    const float samp = amp / norm;
    const float phase = atan2f(iw, rw);
    const float sphi = sinf(phase);
    const float cphi = cosf(phase);
    const float snc = (phase != 0.0f) ? (sphi / phase) : 1.0f;  // sinc(phase/pi)
    Wout[k * QMAX + t] = (samp * sphi * ph[0]) * (samp * cphi * ph[1]) * (samp * snc * ph[2]);
}

// ---------------- Kernel 2: high-occupancy FIR conv -> ws rows ----------------
// Block = (bk, e): bk = b*16+k row, e = eighth of the nonzero span.
// Outputs p in [1920 + e*272, 1920 + (e+1)*272).  2048 blocks = 8/CU -> 32 waves/CU.
// ws[bk][p] = sum_q x[bk][p+q-2047] * W[k][q]. Zero prefix never written.
__global__ __launch_bounds__(256) void conv_e(const float* __restrict__ x,
                                              const float* __restrict__ W,
                                              float* __restrict__ ws) {
    __shared__ __attribute__((aligned(16))) float xs[XS_SZ];
    __shared__ __attribute__((aligned(16))) float Wl[QMAX];

    const int blk = blockIdx.x;
    const int bk = blk >> 3;          // 0..255
    const int e = blk & 7;            // 0..7
    const int k = bk & 15;
    const int tid = threadIdx.x;
    const int P0 = ZCUT + e * ESPAN;  // first output of this span
    const int x0 = P0 - 2047;         // e=0: -127 (zeros), else >= 145

    if (tid < QMAX) Wl[tid] = W[k * QMAX + tid];

    // stage xs[i] = x[x0+i], i in [0,400); zeros where x0+i < 0 (only e=0)
    const float* xrow = x + (size_t)bk * 4096;
    #pragma unroll
    for (int s = 0; s < 2; ++s) {
        const int li = tid + 256 * s;
        if (li < XS_SZ) {
            const int g = x0 + li;                       // max g = 1777+399 = 2176 < 4096
            xs[li] = (g >= 0) ? xrow[g] : 0.0f;
        }
    }
    __syncthreads();

    // conv: threads 0..EF4-1 produce one float4 each
    if (tid < EF4) {
        const int p = P0 + 4 * tid;
        const int base = 4 * tid;     // xs[base+q] = x[p+q-2047]
        float acc[4] = {0.0f, 0.0f, 0.0f, 0.0f};
        float4 xcur = *(const float4*)&xs[base];
        #pragma unroll 4
        for (int q = 0; q < QMAX; q += 4) {
            float4 w4 = *(const float4*)&Wl[q];
            float4 xnxt = *(const float4*)&xs[base + q + 4];
            float win[8] = {xcur.x, xcur.y, xcur.z, xcur.w,
                            xnxt.x, xnxt.y, xnxt.z, xnxt.w};
            float wv[4] = {w4.x, w4.y, w4.z, w4.w};
            #pragma unroll
            for (int j = 0; j < 4; ++j) {
                #pragma unroll
                for (int r = 0; r < 4; ++r) {
                    acc[r] = fmaf(win[r + j], wv[j], acc[r]);
                }
            }
            xcur = xnxt;
        }
        float* wrow = ws + (size_t)bk * 4096;
        *(float4*)&wrow[p] = make_float4(acc[0], acc[1], acc[2], acc[3]);
    }
}

// ---------------- Kernel 3: fill-shaped replicate ws -> out (proven 9.8 us) --------
__global__ __launch_bounds__(256) void replicate_rows(const float* __restrict__ ws,
                                                      float* __restrict__ out) {
    const int g = blockIdx.x;        // 0..511
    const int m0 = g * 8;
    const int b = m0 >> 8;           // all 8 rows share b (8 | 256)
    const int tid = threadIdx.x;
    const vfloat4 zero = {0.0f, 0.0f, 0.0f, 0.0f};

    #pragma unroll
    for (int r = 0; r < 8; ++r) {
        const int m = m0 + r;
        const int k = m & 15;
        const float* __restrict__ src = ws + ((size_t)b * 16 + k) * 4096;
        float* __restrict__ dst = out + (size_t)m * 4096;
        #pragma unroll
        for (int v = 0; v < 4; ++v) {
            const int ei = 4 * (tid + 256 * v);
            vfloat4 val = (ei >= ZCUT) ? *(const vfloat4*)&src[ei] : zero;
            __builtin_nontemporal_store(val, (vfloat4*)&dst[ei]);
        }
    }
}

extern "C" void kernel_launch(void* const* d_in, const int* in_sizes, int n_in,
                              void* d_out, int out_size, void* d_ws, size_t ws_size,
                              hipStream_t stream) {
    const float* x          = (const float*)d_in[0];
    const float* scales     = (const float*)d_in[1];
    const float* f_mod      = (const float*)d_in[2];
    const float* poly_mod   = (const float*)d_in[3];
    const float* exp_mod    = (const float*)d_in[4];
    const float* frac_order = (const float*)d_in[5];
    const float* phase_mod  = (const float*)d_in[6];
    const int*   istep      = (const int*)d_in[7];
    float* out = (float*)d_out;
    float* wsd = (float*)d_ws;
    float* Wtab = wsd;               // 16*128 floats at ws[0..2048)
    float* rows = wsd + 4096;        // 256 rows x 4096 floats = 4 MB

    wavelet_build<<<dim3(16), dim3(QMAX), 0, stream>>>(
        scales, f_mod, poly_mod, exp_mod, frac_order, phase_mod, istep, Wtab);

    conv_e<<<dim3(2048), dim3(256), 0, stream>>>(x, Wtab, rows);

    replicate_rows<<<dim3(512), dim3(256), 0, stream>>>(rows, out);
}